// Round 1
// baseline (147.423 us; speedup 1.0000x reference)
//
#include <hip/hip_runtime.h>

// ANFIS layer: B=32768, I=6, T=4, R=4^6=4096 rules, consequents [R, 7].
// out[b] = (sum_r w[b,r] * f[b,r]) / (sum_r w[b,r] + 1e-8)
//   w[b,r]   = prod_i mu[b, i, digit_i(r)]       (digit_0 most significant, base 4)
//   f[b,r]   = sum_{j<6} x[b,j]*C[r,j] + C[r,6]
//
// Factorization: r = h*64 + l  (h = digits 0..2, l = digits 3..5)
//   w = PH[b,h] * PT[b,l]
//   den[b] = (sum_h PH) * (sum_l PT)                       [separable]
//   num[b] = sum_j xaug_j * sum_l PT[l] * sum_k PH[k]*C[k*64+l, j]
// Lane l owns low-triple l; k-loop over high-triples; PH[k] via v_readlane.

#define G   8            // batch elements per wave
#define WPB 4            // waves per block
#define BLOCK (WPB * 64)

__launch_bounds__(BLOCK, 4)
__global__ void anfis_kernel(const float* __restrict__ x,
                             const float* __restrict__ centers,
                             const float* __restrict__ sigmas,
                             const float* __restrict__ cons,
                             float* __restrict__ out, int B) {
    // 1024 rules/chunk, stride 8 floats (pad) so each row = 2x ds_read_b128
    __shared__ float ldsC[1024 * 8];

    const int lane = threadIdx.x & 63;
    const int wid  = blockIdx.x * WPB + (threadIdx.x >> 6);
    const long b0  = (long)wid * G;

    // lane's digit triple (used for BOTH its head-combo and tail-combo roles)
    const int d0 = (lane >> 4) & 3;
    const int d1 = (lane >> 2) & 3;
    const int d2 = lane & 3;

    // per-lane center / 1/(2 s^2) for its 6 (input, term) selections
    float cen[6], inv[6];
    {
        const int t[6] = {d0, d1, d2, d0, d1, d2};
#pragma unroll
        for (int i = 0; i < 6; ++i) {
            cen[i] = centers[i * 4 + t[i]];
            float s = fabsf(sigmas[i * 4 + t[i]]) + 1e-6f;
            inv[i] = 0.5f / (s * s);
        }
    }

    // head product PH (this lane = high-triple `lane`) and tail product PT
    float ph[G], pt[G];
#pragma unroll
    for (int g = 0; g < G; ++g) {
        long b = b0 + g;
        if (b < B) {
            float m[6];
#pragma unroll
            for (int i = 0; i < 6; ++i) {
                float d = x[b * 6 + i] - cen[i];
                m[i] = __expf(-d * d * inv[i]);
            }
            ph[g] = m[0] * m[1] * m[2];
            pt[g] = m[3] * m[4] * m[5];
        } else {
            ph[g] = 0.f;
            pt[g] = 0.f;
        }
    }

    // S[g][j] = sum_k PH[g,k] * C[k*64 + lane, j]
    float S[G][7];
#pragma unroll
    for (int g = 0; g < G; ++g)
#pragma unroll
        for (int j = 0; j < 7; ++j) S[g][j] = 0.f;

    for (int c = 0; c < 4; ++c) {
        __syncthreads();
        // stage rows [c*1024, c*1024+1024): 7168 floats, coalesced, stride-8 in LDS
        const float* src = cons + c * 7168;
#pragma unroll
        for (int i = 0; i < 28; ++i) {
            int idx = (int)threadIdx.x + i * BLOCK;   // 0..7167
            int row = idx / 7;                        // magic-mul
            int col = idx - row * 7;
            ldsC[row * 8 + col] = src[idx];
        }
        __syncthreads();

        for (int krel = 0; krel < 16; ++krel) {
            const int k = c * 16 + krel;
            const float4* p = (const float4*)&ldsC[(krel * 64 + lane) * 8];
            float4 c0 = p[0];
            float4 c1 = p[1];
#pragma unroll
            for (int g = 0; g < G; ++g) {
                float pk = __uint_as_float(
                    __builtin_amdgcn_readlane(__float_as_uint(ph[g]), k));
                S[g][0] = fmaf(pk, c0.x, S[g][0]);
                S[g][1] = fmaf(pk, c0.y, S[g][1]);
                S[g][2] = fmaf(pk, c0.z, S[g][2]);
                S[g][3] = fmaf(pk, c0.w, S[g][3]);
                S[g][4] = fmaf(pk, c1.x, S[g][4]);
                S[g][5] = fmaf(pk, c1.y, S[g][5]);
                S[g][6] = fmaf(pk, c1.z, S[g][6]);
            }
        }
    }

    // epilogue: q = PT * (xaug . S); num = wavesum(q); den = wavesum(PH)*wavesum(PT)
#pragma unroll
    for (int g = 0; g < G; ++g) {
        long b = b0 + g;
        float q = 0.f;
        float hp = ph[g];
        float tp = pt[g];
        if (b < B) {
            float dotv = S[g][6];
#pragma unroll
            for (int i = 0; i < 6; ++i) dotv = fmaf(x[b * 6 + i], S[g][i], dotv);
            q = tp * dotv;
        }
#pragma unroll
        for (int off = 32; off; off >>= 1) {
            q  += __shfl_xor(q, off);
            hp += __shfl_xor(hp, off);
            tp += __shfl_xor(tp, off);
        }
        if (lane == 0 && b < B) out[b] = q / (hp * tp + 1e-8f);
    }
}

extern "C" void kernel_launch(void* const* d_in, const int* in_sizes, int n_in,
                              void* d_out, int out_size, void* d_ws, size_t ws_size,
                              hipStream_t stream) {
    const float* x       = (const float*)d_in[0];
    const float* centers = (const float*)d_in[1];
    const float* sigmas  = (const float*)d_in[2];
    const float* cons    = (const float*)d_in[3];
    float* out = (float*)d_out;

    int B = in_sizes[0] / 6;                 // 32768
    int waves  = (B + G - 1) / G;            // 4096
    int blocks = (waves + WPB - 1) / WPB;    // 1024
    anfis_kernel<<<blocks, BLOCK, 0, stream>>>(x, centers, sigmas, cons, out, B);
}

// Round 2
// 106.519 us; speedup vs baseline: 1.3840x; 1.3840x over previous
//
#include <hip/hip_runtime.h>

// ANFIS layer: B=32768, I=6, T=4, R=4^6=4096 rules, consequents [R, 7].
// out[b] = (sum_r w*f) / (sum_r w + 1e-8),  w = PH[b,h]*PT[b,l]  (r = h*64+l)
// den[b] = (sum_h PH)*(sum_l PT);  num via S[g][j] = sum_k PH[k]*C[k*64+lane, j].
// Lane l owns low-triple l; PH[k] fetched with v_readlane (k uniform).
// C staged to LDS as bf16 rows of 8 (16 B) -> conflict-free ds_read_b128.

#define G   8            // batch elements per wave
#define WPB 4            // waves per block
#define BLOCK (WPB * 64)
#define CHUNK_ROWS 2048  // rules per LDS chunk (x2 chunks = 4096), 32 KB

__device__ __forceinline__ unsigned int bf16rne(float f) {
    unsigned int u = __float_as_uint(f);
    u += 0x7fffu + ((u >> 16) & 1u);
    return u >> 16;
}

// pack consequents [4096,7] fp32 -> [4096] uint4 (8 bf16/row, col7=0) in ws
__global__ void anfis_prep(const float* __restrict__ cons, uint4* __restrict__ ws) {
    int r = blockIdx.x * blockDim.x + threadIdx.x;
    if (r < 4096) {
        unsigned int h[8];
#pragma unroll
        for (int j = 0; j < 7; ++j) h[j] = bf16rne(cons[r * 7 + j]);
        h[7] = 0;
        uint4 v;
        v.x = h[0] | (h[1] << 16);
        v.y = h[2] | (h[3] << 16);
        v.z = h[4] | (h[5] << 16);
        v.w = h[6];
        ws[r] = v;
    }
}

__launch_bounds__(BLOCK, 3)
__global__ void anfis_kernel(const float* __restrict__ x,
                             const float* __restrict__ centers,
                             const float* __restrict__ sigmas,
                             const float* __restrict__ cons,
                             const uint4* __restrict__ consbf,  // prepacked in ws (or null)
                             float* __restrict__ out, int B) {
    __shared__ uint4 ldsC[CHUNK_ROWS];   // 8 bf16 per row, 32 KB

    const int lane = threadIdx.x & 63;
    const int wid  = blockIdx.x * WPB + (threadIdx.x >> 6);
    const long b0  = (long)wid * G;

    const int d0 = (lane >> 4) & 3;
    const int d1 = (lane >> 2) & 3;
    const int d2 = lane & 3;

    float cen[6], inv[6];
    {
        const int t[6] = {d0, d1, d2, d0, d1, d2};
#pragma unroll
        for (int i = 0; i < 6; ++i) {
            cen[i] = centers[i * 4 + t[i]];
            float s = fabsf(sigmas[i * 4 + t[i]]) + 1e-6f;
            inv[i] = 0.5f / (s * s);
        }
    }

    // head product PH (lane = high triple) and tail product PT (lane = low triple)
    float ph[G], pt[G];
#pragma unroll
    for (int g = 0; g < G; ++g) {
        long b = b0 + g;
        if (b < B) {
            float m[6];
#pragma unroll
            for (int i = 0; i < 6; ++i) {
                float d = x[b * 6 + i] - cen[i];
                m[i] = __expf(-d * d * inv[i]);
            }
            ph[g] = m[0] * m[1] * m[2];
            pt[g] = m[3] * m[4] * m[5];
        } else {
            ph[g] = 0.f;
            pt[g] = 0.f;
        }
    }

    float S[G][7];
#pragma unroll
    for (int g = 0; g < G; ++g)
#pragma unroll
        for (int j = 0; j < 7; ++j) S[g][j] = 0.f;

    for (int c = 0; c < 2; ++c) {
        __syncthreads();
        if (consbf) {
            // fast path: coalesced uint4 copy, conflict-free b128 writes
            const uint4* src = consbf + c * CHUNK_ROWS;
#pragma unroll
            for (int j = 0; j < CHUNK_ROWS / BLOCK; ++j) {
                int i = (int)threadIdx.x + j * BLOCK;
                ldsC[i] = src[i];
            }
        } else {
            // fallback: repack fp32 cons -> bf16 rows in-kernel
            unsigned short* lw = (unsigned short*)ldsC;
            const float4* src = (const float4*)(cons + c * CHUNK_ROWS * 7);
#pragma unroll
            for (int j = 0; j < (CHUNK_ROWS * 7 / 4) / BLOCK; ++j) {
                int idx = (int)threadIdx.x + j * BLOCK;
                float4 v = src[idx];
                int pos = idx * 4;
                float e[4] = {v.x, v.y, v.z, v.w};
#pragma unroll
                for (int q = 0; q < 4; ++q) {
                    int p = pos + q;
                    int row = p / 7;
                    int col = p - row * 7;
                    lw[row * 8 + col] = (unsigned short)bf16rne(e[q]);
                }
            }
        }
        __syncthreads();

#pragma unroll 4
        for (int krel = 0; krel < CHUNK_ROWS / 64; ++krel) {  // 32
            const int k = c * (CHUNK_ROWS / 64) + krel;
            uint4 q = ldsC[krel * 64 + lane];
            float c0 = __uint_as_float(q.x << 16);
            float c1 = __uint_as_float(q.x & 0xffff0000u);
            float c2 = __uint_as_float(q.y << 16);
            float c3 = __uint_as_float(q.y & 0xffff0000u);
            float c4 = __uint_as_float(q.z << 16);
            float c5 = __uint_as_float(q.z & 0xffff0000u);
            float c6 = __uint_as_float(q.w << 16);
#pragma unroll
            for (int g = 0; g < G; ++g) {
                float pk = __uint_as_float(
                    __builtin_amdgcn_readlane(__float_as_uint(ph[g]), k));
                S[g][0] = fmaf(pk, c0, S[g][0]);
                S[g][1] = fmaf(pk, c1, S[g][1]);
                S[g][2] = fmaf(pk, c2, S[g][2]);
                S[g][3] = fmaf(pk, c3, S[g][3]);
                S[g][4] = fmaf(pk, c4, S[g][4]);
                S[g][5] = fmaf(pk, c5, S[g][5]);
                S[g][6] = fmaf(pk, c6, S[g][6]);
            }
        }
    }

    // epilogue: q = PT * (xaug . S); num = wavesum(q); den = wavesum(PH)*wavesum(PT)
#pragma unroll
    for (int g = 0; g < G; ++g) {
        long b = b0 + g;
        float q = 0.f;
        float hp = ph[g];
        float tp = pt[g];
        if (b < B) {
            float dotv = S[g][6];
#pragma unroll
            for (int i = 0; i < 6; ++i) dotv = fmaf(x[b * 6 + i], S[g][i], dotv);
            q = tp * dotv;
        }
#pragma unroll
        for (int off = 32; off; off >>= 1) {
            q  += __shfl_xor(q, off);
            hp += __shfl_xor(hp, off);
            tp += __shfl_xor(tp, off);
        }
        if (lane == 0 && b < B) out[b] = q / (hp * tp + 1e-8f);
    }
}

extern "C" void kernel_launch(void* const* d_in, const int* in_sizes, int n_in,
                              void* d_out, int out_size, void* d_ws, size_t ws_size,
                              hipStream_t stream) {
    const float* x       = (const float*)d_in[0];
    const float* centers = (const float*)d_in[1];
    const float* sigmas  = (const float*)d_in[2];
    const float* cons    = (const float*)d_in[3];
    float* out = (float*)d_out;

    int B = in_sizes[0] / 6;                 // 32768
    int waves  = (B + G - 1) / G;            // 4096
    int blocks = (waves + WPB - 1) / WPB;    // 1024

    uint4* consbf = nullptr;
    if (ws_size >= 4096 * sizeof(uint4)) {
        consbf = (uint4*)d_ws;
        anfis_prep<<<16, 256, 0, stream>>>(cons, consbf);
    }
    anfis_kernel<<<blocks, BLOCK, 0, stream>>>(x, centers, sigmas, cons, consbf,
                                               out, B);
}

// Round 3
// 103.607 us; speedup vs baseline: 1.4229x; 1.0281x over previous
//
#include <hip/hip_runtime.h>

// ANFIS layer: B=32768, I=6, T=4, R=4^6=4096 rules, consequents [R, 7].
// out[b] = (sum_r w*f) / (sum_r w + 1e-8),  w = PH[b,h]*PT[b,l]  (r = h*64+l)
// den[b] = (sum_h PH)*(sum_l PT);  num via S[g][j] = sum_k PH[k]*C[k*64+lane, j].
// Lane l owns low-triple l; PH[k] fetched with v_readlane (k uniform).
// C staged to LDS as bf16 rows of 8 (16 B) -> conflict-free ds_read_b128.
// G=4 keeps live VGPRs ~60-70 so the allocator cannot spill (round-2 lesson:
// it targets its own occupancy and spills S[8][7] regardless of launch_bounds).

#define G   4            // batch elements per wave
#define WPB 8            // waves per block
#define BLOCK (WPB * 64)
#define CHUNK_ROWS 2048  // rules per LDS chunk (x2 chunks = 4096), 32 KB

__device__ __forceinline__ unsigned int bf16rne(float f) {
    unsigned int u = __float_as_uint(f);
    u += 0x7fffu + ((u >> 16) & 1u);
    return u >> 16;
}

// pack consequents [4096,7] fp32 -> [4096] uint4 (8 bf16/row, col7=0) in ws
__global__ void anfis_prep(const float* __restrict__ cons, uint4* __restrict__ ws) {
    int r = blockIdx.x * blockDim.x + threadIdx.x;
    if (r < 4096) {
        unsigned int h[8];
#pragma unroll
        for (int j = 0; j < 7; ++j) h[j] = bf16rne(cons[r * 7 + j]);
        h[7] = 0;
        uint4 v;
        v.x = h[0] | (h[1] << 16);
        v.y = h[2] | (h[3] << 16);
        v.z = h[4] | (h[5] << 16);
        v.w = h[6];
        ws[r] = v;
    }
}

__launch_bounds__(BLOCK)
__global__ void anfis_kernel(const float* __restrict__ x,
                             const float* __restrict__ centers,
                             const float* __restrict__ sigmas,
                             const float* __restrict__ cons,
                             const uint4* __restrict__ consbf,  // prepacked in ws (or null)
                             float* __restrict__ out, int B) {
    __shared__ uint4 ldsC[CHUNK_ROWS];   // 8 bf16 per row, 32 KB

    const int lane = threadIdx.x & 63;
    const int wid  = blockIdx.x * WPB + (threadIdx.x >> 6);
    const long b0  = (long)wid * G;

    const int d0 = (lane >> 4) & 3;
    const int d1 = (lane >> 2) & 3;
    const int d2 = lane & 3;

    float cen[6], inv[6];
    {
        const int t[6] = {d0, d1, d2, d0, d1, d2};
#pragma unroll
        for (int i = 0; i < 6; ++i) {
            cen[i] = centers[i * 4 + t[i]];
            float s = fabsf(sigmas[i * 4 + t[i]]) + 1e-6f;
            inv[i] = 0.5f / (s * s);
        }
    }

    // head product PH (lane = high triple) and tail product PT (lane = low triple)
    float ph[G], pt[G];
#pragma unroll
    for (int g = 0; g < G; ++g) {
        long b = b0 + g;
        if (b < B) {
            float m[6];
#pragma unroll
            for (int i = 0; i < 6; ++i) {
                float d = x[b * 6 + i] - cen[i];
                m[i] = __expf(-d * d * inv[i]);
            }
            ph[g] = m[0] * m[1] * m[2];
            pt[g] = m[3] * m[4] * m[5];
        } else {
            ph[g] = 0.f;
            pt[g] = 0.f;
        }
    }

    float S[G][7];
#pragma unroll
    for (int g = 0; g < G; ++g)
#pragma unroll
        for (int j = 0; j < 7; ++j) S[g][j] = 0.f;

    for (int c = 0; c < 2; ++c) {
        __syncthreads();
        if (consbf) {
            // fast path: coalesced uint4 copy, conflict-free b128 writes
            const uint4* src = consbf + c * CHUNK_ROWS;
#pragma unroll
            for (int j = 0; j < CHUNK_ROWS / BLOCK; ++j) {
                int i = (int)threadIdx.x + j * BLOCK;
                ldsC[i] = src[i];
            }
        } else {
            // fallback: repack fp32 cons -> bf16 rows in-kernel
            unsigned short* lw = (unsigned short*)ldsC;
            const float4* src = (const float4*)(cons + c * CHUNK_ROWS * 7);
#pragma unroll
            for (int j = 0; j < (CHUNK_ROWS * 7 / 4) / BLOCK; ++j) {
                int idx = (int)threadIdx.x + j * BLOCK;
                float4 v = src[idx];
                int pos = idx * 4;
                float e[4] = {v.x, v.y, v.z, v.w};
#pragma unroll
                for (int q = 0; q < 4; ++q) {
                    int p = pos + q;
                    int row = p / 7;
                    int col = p - row * 7;
                    lw[row * 8 + col] = (unsigned short)bf16rne(e[q]);
                }
            }
        }
        __syncthreads();

#pragma unroll 4
        for (int krel = 0; krel < CHUNK_ROWS / 64; ++krel) {  // 32
            const int k = c * (CHUNK_ROWS / 64) + krel;
            uint4 q = ldsC[krel * 64 + lane];
            float c0 = __uint_as_float(q.x << 16);
            float c1 = __uint_as_float(q.x & 0xffff0000u);
            float c2 = __uint_as_float(q.y << 16);
            float c3 = __uint_as_float(q.y & 0xffff0000u);
            float c4 = __uint_as_float(q.z << 16);
            float c5 = __uint_as_float(q.z & 0xffff0000u);
            float c6 = __uint_as_float(q.w << 16);
#pragma unroll
            for (int g = 0; g < G; ++g) {
                float pk = __uint_as_float(
                    __builtin_amdgcn_readlane(__float_as_uint(ph[g]), k));
                S[g][0] = fmaf(pk, c0, S[g][0]);
                S[g][1] = fmaf(pk, c1, S[g][1]);
                S[g][2] = fmaf(pk, c2, S[g][2]);
                S[g][3] = fmaf(pk, c3, S[g][3]);
                S[g][4] = fmaf(pk, c4, S[g][4]);
                S[g][5] = fmaf(pk, c5, S[g][5]);
                S[g][6] = fmaf(pk, c6, S[g][6]);
            }
        }
    }

    // epilogue: q = PT * (xaug . S); num = wavesum(q); den = wavesum(PH)*wavesum(PT)
#pragma unroll
    for (int g = 0; g < G; ++g) {
        long b = b0 + g;
        float q = 0.f;
        float hp = ph[g];
        float tp = pt[g];
        if (b < B) {
            float dotv = S[g][6];
#pragma unroll
            for (int i = 0; i < 6; ++i) dotv = fmaf(x[b * 6 + i], S[g][i], dotv);
            q = tp * dotv;
        }
#pragma unroll
        for (int off = 32; off; off >>= 1) {
            q  += __shfl_xor(q, off);
            hp += __shfl_xor(hp, off);
            tp += __shfl_xor(tp, off);
        }
        if (lane == 0 && b < B) out[b] = q / (hp * tp + 1e-8f);
    }
}

extern "C" void kernel_launch(void* const* d_in, const int* in_sizes, int n_in,
                              void* d_out, int out_size, void* d_ws, size_t ws_size,
                              hipStream_t stream) {
    const float* x       = (const float*)d_in[0];
    const float* centers = (const float*)d_in[1];
    const float* sigmas  = (const float*)d_in[2];
    const float* cons    = (const float*)d_in[3];
    float* out = (float*)d_out;

    int B = in_sizes[0] / 6;                 // 32768
    int waves  = (B + G - 1) / G;            // 8192
    int blocks = (waves + WPB - 1) / WPB;    // 1024

    uint4* consbf = nullptr;
    if (ws_size >= 4096 * sizeof(uint4)) {
        consbf = (uint4*)d_ws;
        anfis_prep<<<16, 256, 0, stream>>>(cons, consbf);
    }
    anfis_kernel<<<blocks, BLOCK, 0, stream>>>(x, centers, sigmas, cons, consbf,
                                               out, B);
}

// Round 4
// 80.913 us; speedup vs baseline: 1.8220x; 1.2805x over previous
//
#include <hip/hip_runtime.h>

// ANFIS layer via MFMA. B=32768, I=6, T=4, R=4096, C=[4096,7].
// r = h*64 + l (h=digits 0-2 from inputs 0-2, l=digits 3-5 from inputs 3-5)
//   w[b,r] = PH[b,h]*PT[b,l];  f[b,r] = sum_j xaug[b,j]*C[r,j]
//   num[b] = sum_{h,l,j} PH[h]*PT[l]*xaug[j]*C[h*64+l,j]  = PH[b]^T * C2 * u[b]
//     where u[b, l*8+j] = PT[b,l]*xaug[b,j],  C2[h, l*8+j] = C[h*64+l, j]
//   den[b] = (sum_h PH)*(sum_l PT) + 1e-8
// GEMM: V[b, n] = sum_c u[b,c]*Bm[c,n]; n<64: Bm=C2^T; n==64: Bm=indicator((c&7)==6)
//   -> V[b,64] = sum_l PT[b,l]*xaug[b,6] = sumPT[b]   (den for free)
// Then num = sum_{n<64} PH[b,n]*V[b,n] (PH fp32), sumPH = sum_n PH[b,n].
// U is split hi/lo bf16 (truncation split, exact to ~2^-16); C bf16 (r2/r3: 3.9e-3 ok).
// MFMA 16x16x32 bf16 layouts (guide-verified): A[m=lane&15][k=q*8+j],
// B[k=q*8+j][n=lane&15], D: col=lane&15, row=q*4+reg  (q = lane>>4).

typedef __attribute__((ext_vector_type(8))) short bf16x8;
typedef __attribute__((ext_vector_type(4))) float f32x4;

#define THREADS 512
#define BPB     128            // batch rows per block
#define C2T_ROW_W 260          // u32 words per C2T row (512 bf16 data + 8 pad)
#define C2T_WORDS (64 * C2T_ROW_W)      // 16640 u32
#define PH_STR  66             // fp32 words per PH row (64 + 2 pad)
#define PTT_STR 132            // fp32 words per PTT row (128 + 4 pad)
#define LDS_BYTES ((C2T_WORDS + BPB * PH_STR + 64 * PTT_STR) * 4)   // 134144

__device__ __forceinline__ unsigned int bf16rne(float f) {
    unsigned int u = __float_as_uint(f);
    u += 0x7fffu + ((u >> 16) & 1u);
    return u >> 16;
}

// pack C[4096,7] fp32 -> ws as bf16 C2T[n=0..63][c=0..511], c = l*8+j (j=7 -> 0).
// Unpadded (64*256 u32 = 65536 B); main kernel inserts the row pad while staging.
__global__ void anfis_prep(const float* __restrict__ cons, unsigned int* __restrict__ ws) {
    int idx = blockIdx.x * blockDim.x + threadIdx.x;   // [0, 16384)
    if (idx >= 64 * 256) return;
    int n = idx >> 8;
    int w = idx & 255;
    int c0 = w * 2;
    unsigned int h0 = 0, h1 = 0;
    int l = c0 >> 3, j = c0 & 7;
    if (j < 7) h0 = bf16rne(cons[(n * 64 + l) * 7 + j]);
    l = (c0 + 1) >> 3; j = (c0 + 1) & 7;
    if (j < 7) h1 = bf16rne(cons[(n * 64 + l) * 7 + j]);
    ws[idx] = h0 | (h1 << 16);
}

extern __shared__ unsigned int smem[];

__launch_bounds__(THREADS, 1)
__global__ void anfis_mfma(const float* __restrict__ x,
                           const float* __restrict__ centers,
                           const float* __restrict__ sigmas,
                           const unsigned int* __restrict__ wsC,
                           float* __restrict__ out, int B) {
    unsigned int* C2T = smem;                          // [64][260] u32 (bf16 pairs)
    float* PH  = (float*)(smem + C2T_WORDS);           // [128][66] fp32
    float* PTT = PH + BPB * PH_STR;                    // [64][132] fp32 (l-major)

    const int tid  = threadIdx.x;
    const int lane = tid & 63;
    const int wv   = tid >> 6;                         // wave 0..7
    const long blockbase = (long)blockIdx.x * BPB;

    // ---- stage C2T from ws, inserting row pad (stride 260 words) ----
    for (int i = tid; i < C2T_WORDS; i += THREADS) {
        int n  = i / C2T_ROW_W;
        int ww = i - n * C2T_ROW_W;
        C2T[i] = (ww < 256) ? wsC[(n << 8) + ww] : 0u;
    }

    // ---- phase 1: memberships. lane = triple index for both PH and PT ----
    {
        const int d0 = (lane >> 4) & 3, d1 = (lane >> 2) & 3, d2 = lane & 3;
        float cen[6], inv[6];
        const int t6[6] = {d0, d1, d2, d0, d1, d2};
#pragma unroll
        for (int i = 0; i < 6; ++i) {
            cen[i] = centers[i * 4 + t6[i]];
            float s = fabsf(sigmas[i * 4 + t6[i]]) + 1e-6f;
            inv[i] = 0.5f / (s * s);
        }
#pragma unroll 2
        for (int g = 0; g < 16; ++g) {
            int bl = wv * 16 + g;
            long b = blockbase + bl;
            if (b >= B) b = B - 1;
            float m[6];
#pragma unroll
            for (int i = 0; i < 6; ++i) {
                float d = x[b * 6 + i] - cen[i];
                m[i] = __expf(-d * d * inv[i]);
            }
            PH[bl * PH_STR + lane]  = m[0] * m[1] * m[2];
            PTT[lane * PTT_STR + bl] = m[3] * m[4] * m[5];
        }
    }
    __syncthreads();

    // ---- phase 2: GEMM V = U @ Bm, wave owns 16 batch rows m0..m0+15 ----
    const int t = lane & 15, q = lane >> 4;
    const int m0 = wv * 16;

    float xa[8];
    {
        long bm = blockbase + m0 + t;
        if (bm >= B) bm = B - 1;
#pragma unroll
        for (int j = 0; j < 6; ++j) xa[j] = x[bm * 6 + j];
        xa[6] = 1.f;
        xa[7] = 0.f;
    }

    union U4 { unsigned int u[4]; bf16x8 v; };
    U4 B4;                                      // den indicator column (n-local 0)
    B4.u[0] = B4.u[1] = B4.u[2] = 0u;
    B4.u[3] = (t == 0) ? 0x00003f80u : 0u;      // element 6 = bf16(1.0) iff n==64

    f32x4 Dn[4], D4;
#pragma unroll
    for (int nt = 0; nt < 4; ++nt) Dn[nt] = (f32x4){0.f, 0.f, 0.f, 0.f};
    D4 = (f32x4){0.f, 0.f, 0.f, 0.f};

    const unsigned short* C2Ts = (const unsigned short*)C2T;

#pragma unroll 2
    for (int kt = 0; kt < 16; ++kt) {
        float ptv = PTT[(kt * 4 + q) * PTT_STR + m0 + t];
        U4 Ah, Al;
#pragma unroll
        for (int jp = 0; jp < 4; ++jp) {
            float u0 = ptv * xa[2 * jp];
            float u1 = ptv * xa[2 * jp + 1];
            unsigned int b0 = __float_as_uint(u0), b1 = __float_as_uint(u1);
            unsigned int t0 = b0 & 0xffff0000u, t1 = b1 & 0xffff0000u;
            float l0 = u0 - __uint_as_float(t0);
            float l1 = u1 - __uint_as_float(t1);
            Ah.u[jp] = (b0 >> 16) | t1;
            Al.u[jp] = (__float_as_uint(l0) >> 16) | (__float_as_uint(l1) & 0xffff0000u);
        }
#pragma unroll
        for (int nt = 0; nt < 4; ++nt) {
            bf16x8 Bf = *(const bf16x8*)&C2Ts[(nt * 16 + t) * 520 + kt * 32 + q * 8];
            Dn[nt] = __builtin_amdgcn_mfma_f32_16x16x32_bf16(Ah.v, Bf, Dn[nt], 0, 0, 0);
            Dn[nt] = __builtin_amdgcn_mfma_f32_16x16x32_bf16(Al.v, Bf, Dn[nt], 0, 0, 0);
        }
        D4 = __builtin_amdgcn_mfma_f32_16x16x32_bf16(Ah.v, B4.v, D4, 0, 0, 0);
        D4 = __builtin_amdgcn_mfma_f32_16x16x32_bf16(Al.v, B4.v, D4, 0, 0, 0);
    }

    // ---- epilogue: num = sum_n PH*V, sumPH = sum_n PH, sumPT = butterfly(D4) ----
    float Pn[4] = {0.f, 0.f, 0.f, 0.f};
    float Ps[4] = {0.f, 0.f, 0.f, 0.f};
    float Pd[4];
#pragma unroll
    for (int r = 0; r < 4; ++r) Pd[r] = D4[r];
#pragma unroll
    for (int nt = 0; nt < 4; ++nt)
#pragma unroll
        for (int r = 0; r < 4; ++r) {
            float phv = PH[(m0 + q * 4 + r) * PH_STR + nt * 16 + t];
            Pn[r] = fmaf(phv, Dn[nt][r], Pn[r]);
            Ps[r] += phv;
        }
#pragma unroll
    for (int off = 1; off < 16; off <<= 1)
#pragma unroll
        for (int r = 0; r < 4; ++r) {
            Pn[r] += __shfl_xor(Pn[r], off);
            Ps[r] += __shfl_xor(Ps[r], off);
            Pd[r] += __shfl_xor(Pd[r], off);
        }
    if (t == 0) {
        long bo = blockbase + m0 + q * 4;
        float o[4];
#pragma unroll
        for (int r = 0; r < 4; ++r) o[r] = Pn[r] / (Ps[r] * Pd[r] + 1e-8f);
        if (bo + 3 < B) {
            *(float4*)&out[bo] = make_float4(o[0], o[1], o[2], o[3]);
        } else {
#pragma unroll
            for (int r = 0; r < 4; ++r)
                if (bo + r < B) out[bo + r] = o[r];
        }
    }
}

extern "C" void kernel_launch(void* const* d_in, const int* in_sizes, int n_in,
                              void* d_out, int out_size, void* d_ws, size_t ws_size,
                              hipStream_t stream) {
    const float* x       = (const float*)d_in[0];
    const float* centers = (const float*)d_in[1];
    const float* sigmas  = (const float*)d_in[2];
    const float* cons    = (const float*)d_in[3];
    float* out = (float*)d_out;

    int B = in_sizes[0] / 6;                       // 32768
    unsigned int* wsC = (unsigned int*)d_ws;       // needs 65536 B

    static int attr_set = 0;                       // idempotent; same work every call
    hipFuncSetAttribute(reinterpret_cast<const void*>(anfis_mfma),
                        hipFuncAttributeMaxDynamicSharedMemorySize, LDS_BYTES);
    (void)attr_set;

    anfis_prep<<<64, 256, 0, stream>>>(cons, wsC);
    int blocks = (B + BPB - 1) / BPB;              // 256
    anfis_mfma<<<blocks, THREADS, LDS_BYTES, stream>>>(x, centers, sigmas, wsC,
                                                       out, B);
}

// Round 5
// 69.822 us; speedup vs baseline: 2.1114x; 1.1588x over previous
//
#include <hip/hip_runtime.h>

// ANFIS via MFMA, v5. B=32768, I=6, T=4, R=4096, C=[4096,7].
// r = h*64+l: w = PH[b,h]*PT[b,l]; num = PH^T * C2 * u, u[l*8+j]=PT[l]*xaug[j].
// GEMM V[b,n] = sum_c u[b,c]*B[c,n]; n<64: B=C2^T; indicator col (in-reg B4)
// gives V[b,64]=sumPT. den=(sum PH)*(sum PT)+1e-8.
// v5 changes vs v4 (which was 1 block/CU, 2 waves/SIMD, latency-naked):
//  - B-frags read from prep-packed GLOBAL layout [l=kt*4+q][n][8 bf16] (L2-hot,
//    wave load = 4 contiguous 256B runs) -> no C2T staging, no __syncthreads at all
//  - LDS 134KB -> 35KB (PH/PTT/x only, all wave-local) -> 4 blocks/CU
//  - x staged per-wave via one float4 load inst (kills 96-load chain)
//  - PTT stride 65 (odd): conflict-free writes, <=4-way reads
//  - MFMA order all-hi then all-lo: no back-to-back same-accumulator stalls
// MFMA 16x16x32 bf16 layouts (verified r4): A[m=lane&15][k=q*8+j],
// B[k=q*8+j][n=lane&15], D: col=lane&15, row=q*4+reg (q=lane>>4).

typedef __attribute__((ext_vector_type(8))) short bf16x8;
typedef __attribute__((ext_vector_type(4))) float f32x4;

#define THREADS 256
#define BPB     64             // batch rows per block (16 per wave)
#define PH_STR  66             // fp32 words per PH row
#define PTT_STR 65             // odd stride: bank = (l + b) % 32 on writes

__device__ __forceinline__ unsigned int bf16rne(float f) {
    unsigned int u = __float_as_uint(f);
    u += 0x7fffu + ((u >> 16) & 1u);
    return u >> 16;
}

// ws4[l*64 + n] = 8 bf16 {C[n*64+l, 0..6], 0}   (l = kt*4+q)
__global__ void anfis_prep(const float* __restrict__ cons, uint4* __restrict__ ws) {
    int id = blockIdx.x * blockDim.x + threadIdx.x;   // [0, 4096)
    if (id >= 4096) return;
    int l = id >> 6, n = id & 63;
    const float* src = cons + (n * 64 + l) * 7;
    unsigned int h[8];
#pragma unroll
    for (int j = 0; j < 7; ++j) h[j] = bf16rne(src[j]);
    h[7] = 0;
    uint4 v;
    v.x = h[0] | (h[1] << 16);
    v.y = h[2] | (h[3] << 16);
    v.z = h[4] | (h[5] << 16);
    v.w = h[6] | (h[7] << 16);
    ws[id] = v;
}

__launch_bounds__(THREADS, 4)
__global__ void anfis_mfma(const float* __restrict__ x,
                           const float* __restrict__ centers,
                           const float* __restrict__ sigmas,
                           const uint4* __restrict__ wsC,
                           float* __restrict__ out, int B) {
    __shared__ float  PH[BPB * PH_STR];      // [64][66]  fp32, wave-local rows
    __shared__ float  PTT[64 * PTT_STR];     // [l][65]   fp32, wave-local cols
    __shared__ float4 xs4[BPB * 6 / 4];      // 96 float4 = [64][6] floats

    const int tid  = threadIdx.x;
    const int lane = tid & 63;
    const int wv   = tid >> 6;               // wave 0..3, owns rows wv*16..+15
    const long blockbase = (long)blockIdx.x * BPB;
    float* xs = (float*)xs4;

    // ---- stage this wave's 16 rows of x: 96 floats = 24 float4, one inst ----
    if (lane < 24)
        xs4[wv * 24 + lane] = ((const float4*)x)[blockIdx.x * 96 + wv * 24 + lane];

    // ---- memberships (lane = triple index h and l), wave-local LDS only ----
    {
        const int d0 = (lane >> 4) & 3, d1 = (lane >> 2) & 3, d2 = lane & 3;
        const int t6[6] = {d0, d1, d2, d0, d1, d2};
        float cen[6], inv[6];
#pragma unroll
        for (int i = 0; i < 6; ++i) {
            cen[i] = centers[i * 4 + t6[i]];
            float s = fabsf(sigmas[i * 4 + t6[i]]) + 1e-6f;
            inv[i] = 0.5f / (s * s);
        }
#pragma unroll 4
        for (int g = 0; g < 16; ++g) {
            int bl = wv * 16 + g;
            float m[6];
#pragma unroll
            for (int i = 0; i < 6; ++i) {
                float d = xs[bl * 6 + i] - cen[i];
                m[i] = __expf(-d * d * inv[i]);
            }
            PH[bl * PH_STR + lane]   = m[0] * m[1] * m[2];
            PTT[lane * PTT_STR + bl] = m[3] * m[4] * m[5];
        }
    }
    // no barrier: every LDS word read below was written by this same wave

    // ---- GEMM: V[16 rows][65] = U[16][512] @ B[512][65] ----
    const int t = lane & 15, q = lane >> 4, m0 = wv * 16;

    float xa[8];
#pragma unroll
    for (int j = 0; j < 6; ++j) xa[j] = xs[(m0 + t) * 6 + j];
    xa[6] = 1.f;
    xa[7] = 0.f;

    union U4 { unsigned int u[4]; bf16x8 v; };
    U4 B4;                                   // indicator col: V[.,64] = sumPT
    B4.u[0] = B4.u[1] = B4.u[2] = 0u;
    B4.u[3] = (t == 0) ? 0x00003f80u : 0u;   // element 6 = bf16(1.0) iff n==64

    f32x4 Dn[4], D4;
#pragma unroll
    for (int nt = 0; nt < 4; ++nt) Dn[nt] = (f32x4){0.f, 0.f, 0.f, 0.f};
    D4 = (f32x4){0.f, 0.f, 0.f, 0.f};

#pragma unroll 2
    for (int kt = 0; kt < 16; ++kt) {
        const int l = kt * 4 + q;
        // B-frags for this kt: 4 coalesced 16B loads (t contiguous)
        U4 Bf[4];
#pragma unroll
        for (int nt = 0; nt < 4; ++nt) {
            uint4 bw = wsC[l * 64 + nt * 16 + t];
            Bf[nt].u[0] = bw.x; Bf[nt].u[1] = bw.y;
            Bf[nt].u[2] = bw.z; Bf[nt].u[3] = bw.w;
        }
        float ptv = PTT[l * PTT_STR + m0 + t];
        U4 Ah, Al;
#pragma unroll
        for (int jp = 0; jp < 4; ++jp) {
            float u0 = ptv * xa[2 * jp];
            float u1 = ptv * xa[2 * jp + 1];
            unsigned int b0 = __float_as_uint(u0), b1 = __float_as_uint(u1);
            unsigned int t0 = b0 & 0xffff0000u, t1 = b1 & 0xffff0000u;
            float l0 = u0 - __uint_as_float(t0);
            float l1 = u1 - __uint_as_float(t1);
            Ah.u[jp] = (b0 >> 16) | t1;
            Al.u[jp] = (__float_as_uint(l0) >> 16) | (__float_as_uint(l1) & 0xffff0000u);
        }
        // all-hi then all-lo: 5 independent accumulators between dependent pairs
#pragma unroll
        for (int nt = 0; nt < 4; ++nt)
            Dn[nt] = __builtin_amdgcn_mfma_f32_16x16x32_bf16(Ah.v, Bf[nt].v, Dn[nt], 0, 0, 0);
        D4 = __builtin_amdgcn_mfma_f32_16x16x32_bf16(Ah.v, B4.v, D4, 0, 0, 0);
#pragma unroll
        for (int nt = 0; nt < 4; ++nt)
            Dn[nt] = __builtin_amdgcn_mfma_f32_16x16x32_bf16(Al.v, Bf[nt].v, Dn[nt], 0, 0, 0);
        D4 = __builtin_amdgcn_mfma_f32_16x16x32_bf16(Al.v, B4.v, D4, 0, 0, 0);
    }

    // ---- epilogue: num = sum_n PH*V, sumPH = sum_n PH, sumPT from D4 ----
    float Pn[4] = {0.f, 0.f, 0.f, 0.f};
    float Ps[4] = {0.f, 0.f, 0.f, 0.f};
    float Pd[4];
#pragma unroll
    for (int r = 0; r < 4; ++r) Pd[r] = D4[r];
#pragma unroll
    for (int nt = 0; nt < 4; ++nt)
#pragma unroll
        for (int r = 0; r < 4; ++r) {
            float phv = PH[(m0 + q * 4 + r) * PH_STR + nt * 16 + t];
            Pn[r] = fmaf(phv, Dn[nt][r], Pn[r]);
            Ps[r] += phv;
        }
#pragma unroll
    for (int off = 1; off < 16; off <<= 1)
#pragma unroll
        for (int r = 0; r < 4; ++r) {
            Pn[r] += __shfl_xor(Pn[r], off);
            Ps[r] += __shfl_xor(Ps[r], off);
            Pd[r] += __shfl_xor(Pd[r], off);
        }
    if (t == 0) {
        long bo = blockbase + m0 + q * 4;
        float o[4];
#pragma unroll
        for (int r = 0; r < 4; ++r) o[r] = Pn[r] / (Ps[r] * Pd[r] + 1e-8f);
        if (bo + 3 < B) {
            *(float4*)&out[bo] = make_float4(o[0], o[1], o[2], o[3]);
        } else {
#pragma unroll
            for (int r = 0; r < 4; ++r)
                if (bo + r < B) out[bo + r] = o[r];
        }
    }
}

extern "C" void kernel_launch(void* const* d_in, const int* in_sizes, int n_in,
                              void* d_out, int out_size, void* d_ws, size_t ws_size,
                              hipStream_t stream) {
    const float* x       = (const float*)d_in[0];
    const float* centers = (const float*)d_in[1];
    const float* sigmas  = (const float*)d_in[2];
    const float* cons    = (const float*)d_in[3];
    float* out = (float*)d_out;

    int B = in_sizes[0] / 6;                       // 32768
    uint4* wsC = (uint4*)d_ws;                     // needs 65536 B

    anfis_prep<<<16, 256, 0, stream>>>(cons, wsC);
    int blocks = (B + BPB - 1) / BPB;              // 512
    anfis_mfma<<<blocks, THREADS, 0, stream>>>(x, centers, sigmas, wsC, out, B);
}